// Round 3
// baseline (452.334 us; speedup 1.0000x reference)
//
#include <hip/hip_runtime.h>
#include <cstdint>
#include <cstddef>

#define NTH 256
#define NGT 128
#define BATCH 16
#define NC 80
#define G 16                  // GTs per scan block
#define NCHUNK (NGT / G)      // 8
#define HW0 25600
#define HW1 6400
#define HW2 1600
#define SL0 4                 // hw slices for level 0
#define MAXSL 4

// ws layout (bytes)
#define ACC_OFF   0
#define PACK0_OFF 256
#define PACK1_OFF (PACK0_OFF + BATCH * HW0 * 8)
#define PACK2_OFF (PACK1_OFF + BATCH * HW1 * 8)
#define PART_OFF  (PACK2_OFF + BATCH * HW2 * 8)
#define PART_BYTES (3 * BATCH * NGT * MAXSL * 8)
#define WS_NEEDED (PART_OFF + (size_t)PART_BYTES)
#define WS_NEEDED_NOPACK (256 + (size_t)PART_BYTES)

__device__ __forceinline__ unsigned long long umin64(unsigned long long a, unsigned long long b) {
    return a < b ? a : b;
}

// Prepass: pack each 16-B reg row's xy into a contiguous float2 array.
// 537,600 rows total; float4 read (full line use), float2 write.
__global__ __launch_bounds__(NTH) void pack_kernel(
    const float* __restrict__ reg0, const float* __restrict__ reg1, const float* __restrict__ reg2,
    float2* __restrict__ xy0, float2* __restrict__ xy1, float2* __restrict__ xy2)
{
    int r = blockIdx.x * NTH + threadIdx.x;
    const int N0 = BATCH * HW0, N1 = BATCH * HW1, N2 = BATCH * HW2;
    if (r < N0) {
        float4 v = reinterpret_cast<const float4*>(reg0)[r];
        xy0[r] = make_float2(v.x, v.y);
    } else if (r < N0 + N1) {
        int i = r - N0;
        float4 v = reinterpret_cast<const float4*>(reg1)[i];
        xy1[i] = make_float2(v.x, v.y);
    } else if (r < N0 + N1 + N2) {
        int i = r - N0 - N1;
        float4 v = reinterpret_cast<const float4*>(reg2)[i];
        xy2[i] = make_float2(v.x, v.y);
    }
}

#define EVAL(px, py, idx_) do {                                                   \
    _Pragma("unroll")                                                             \
    for (int g = 0; g < G; ++g) {                                                 \
        float dx = gx[g] - (px), dy = gy[g] - (py);                               \
        float d2 = dx * dx + dy * dy;                                             \
        unsigned long long key =                                                  \
            ((unsigned long long)__float_as_uint(d2) << 32) | (unsigned)(idx_);   \
        kmin[g] = umin64(kmin[g], key);                                           \
    } } while (0)

// Scan: one block per (level, batch, hw-slice, chunk-of-16-GTs).
// Writes per-slice partial argmin keys (u64: d2 bits << 32 | idx -> min gives
// min-d2 with first-index tie-break, exactly matching jnp.argmin).
__global__ __launch_bounds__(NTH) void scan_kernel(
    const float2* __restrict__ xy0, const float2* __restrict__ xy1, const float2* __restrict__ xy2,
    int stride2,  // float2 units between consecutive elements: 1 packed, 2 raw reg rows
    const float* __restrict__ gt_boxes,
    unsigned long long* __restrict__ part)
{
    int x = blockIdx.x;
    int lvl, b, slice, chunk, HW, nsl;
    const float2* src;
    if (x < BATCH * SL0 * NCHUNK) {                       // 512 lvl-0 blocks
        lvl = 0; b = x / (SL0 * NCHUNK);
        int r = x % (SL0 * NCHUNK);
        slice = r / NCHUNK; chunk = r % NCHUNK;
        HW = HW0; nsl = SL0; src = xy0;
    } else if (x < BATCH * SL0 * NCHUNK + BATCH * NCHUNK) { // 128 lvl-1 blocks
        int y = x - BATCH * SL0 * NCHUNK;
        lvl = 1; b = y / NCHUNK; chunk = y % NCHUNK; slice = 0;
        HW = HW1; nsl = 1; src = xy1;
    } else {                                               // 128 lvl-2 blocks
        int y = x - BATCH * SL0 * NCHUNK - BATCH * NCHUNK;
        lvl = 2; b = y / NCHUNK; chunk = y % NCHUNK; slice = 0;
        HW = HW2; nsl = 1; src = xy2;
    }

    const int seg = HW / nsl;          // 6400 / 6400 / 1600
    const int e0 = slice * seg, e1 = e0 + seg;
    const int tid = threadIdx.x, wave = tid >> 6, lane = tid & 63;
    const int n0 = chunk * G;

    // GT xy: block-uniform addresses -> scalar loads (SGPRs)
    float gx[G], gy[G];
#pragma unroll
    for (int g = 0; g < G; ++g) {
        const float* gb = gt_boxes + (size_t)(b * NGT + n0 + g) * 4;
        gx[g] = gb[0]; gy[g] = gb[1];
    }

    unsigned long long kmin[G];
#pragma unroll
    for (int g = 0; g < G; ++g) kmin[g] = ~0ull;

    if (stride2 == 1) {
        // packed: float4 load = 2 consecutive xy pairs, 100% line utilization
        const float4* b4 = reinterpret_cast<const float4*>(src + (size_t)b * HW);
        for (int i = e0 / 2 + tid; i < e1 / 2; i += NTH) {
            float4 p = b4[i];
            int i0 = 2 * i;
            EVAL(p.x, p.y, i0);
            EVAL(p.z, p.w, i0 + 1);
        }
    } else {
        const float2* base = xy0;  // raw mode: src points at reg rows
        base = src + (size_t)b * HW * 2;
        for (int i = e0 + tid; i < e1; i += NTH) {
            float2 p = base[(size_t)i * 2];
            EVAL(p.x, p.y, i);
        }
    }

    // intra-wave butterfly reduction per GT
#pragma unroll
    for (int g = 0; g < G; ++g) {
#pragma unroll
        for (int off = 32; off >= 1; off >>= 1) {
            unsigned long long o = __shfl_down(kmin[g], off, 64);
            kmin[g] = umin64(kmin[g], o);
        }
    }

    __shared__ unsigned long long smem[G][4];
    if (lane == 0) {
#pragma unroll
        for (int g = 0; g < G; ++g) smem[g][wave] = kmin[g];
    }
    __syncthreads();

    if (tid < G) {
        unsigned long long key = umin64(umin64(smem[tid][0], smem[tid][1]),
                                        umin64(smem[tid][2], smem[tid][3]));
        part[((size_t)(lvl * BATCH + b) * NGT + n0 + tid) * MAXSL + slice] = key;
    }
}

// Loss: one wave per (level, batch, gt). Combine slice partials, 80-class
// log-softmax via shuffle reductions, L1 on 4 coords, atomicAdd triple.
__global__ __launch_bounds__(NTH) void loss_kernel(
    const float* __restrict__ cls0, const float* __restrict__ cls1, const float* __restrict__ cls2,
    const float* __restrict__ reg0, const float* __restrict__ reg1, const float* __restrict__ reg2,
    const float* __restrict__ gt_boxes, const int* __restrict__ gt_labels,
    const unsigned long long* __restrict__ part, float* __restrict__ acc)
{
    const int gid = blockIdx.x * 4 + (threadIdx.x >> 6);   // 0..6143
    const int lane = threadIdx.x & 63;
    const int lvl = gid / (BATCH * NGT);
    const int r = gid % (BATCH * NGT);
    const int b = r / NGT, n = r % NGT;

    const float* cls; const float* reg; int HW, S;
    if (lvl == 0)      { cls = cls0; reg = reg0; HW = HW0; S = SL0; }
    else if (lvl == 1) { cls = cls1; reg = reg1; HW = HW1; S = 1; }
    else               { cls = cls2; reg = reg2; HW = HW2; S = 1; }

    const unsigned long long* p = part + (size_t)gid * MAXSL;
    unsigned long long key = p[0];
    for (int s = 1; s < S; ++s) key = umin64(key, p[s]);

    int match = (int)(unsigned)(key & 0xffffffffu);
    float d2min = __uint_as_float((unsigned)(key >> 32));
    bool valid = d2min < 6.25f;  // sqrt(d2) < 2.5

    const int label = gt_labels[b * NGT + n];
    const float* c = cls + ((size_t)b * HW + match) * NC;

    // 80-class log-softmax: lanes 0..63 hold c[lane], lanes 0..15 also c[64+lane]
    float x1 = c[lane];
    float x2 = (lane < NC - 64) ? c[64 + lane] : -INFINITY;
    float mx = fmaxf(x1, x2);
#pragma unroll
    for (int off = 32; off >= 1; off >>= 1) mx = fmaxf(mx, __shfl_xor(mx, off, 64));
    float s = expf(x1 - mx) + ((lane < NC - 64) ? expf(x2 - mx) : 0.0f);
#pragma unroll
    for (int off = 32; off >= 1; off >>= 1) s += __shfl_xor(s, off, 64);

    if (lane == 0 && valid) {
        float xlab = c[label];
        float ce = -(xlab - mx - logf(s));
        const float* gb = gt_boxes + (size_t)(b * NGT + n) * 4;
        const float* gr = reg + ((size_t)b * HW + match) * 4;
        float l1 = fabsf(gr[0] - gb[0]) + fabsf(gr[1] - gb[1]) +
                   fabsf(gr[2] - gb[2]) + fabsf(gr[3] - gb[3]);
        atomicAdd(&acc[0], ce);
        atomicAdd(&acc[1], l1);
        atomicAdd(&acc[2], 1.0f);
    }
}

__global__ void finalize_kernel(const float* __restrict__ acc, float* __restrict__ out) {
    float np = acc[2];
    float denom = fmaxf(np, 1.0f);
    out[0] = acc[0] / denom;
    out[1] = acc[1] / denom;
    out[2] = np;
}

extern "C" void kernel_launch(void* const* d_in, const int* in_sizes, int n_in,
                              void* d_out, int out_size, void* d_ws, size_t ws_size,
                              hipStream_t stream) {
    // Map inputs BY SIZE (dict order interleaves cls/reg; all sizes distinct).
    const float* cls0 = nullptr; const float* cls1 = nullptr; const float* cls2 = nullptr;
    const float* reg0 = nullptr; const float* reg1 = nullptr; const float* reg2 = nullptr;
    const float* gt_boxes = nullptr; const int* gt_labels = nullptr;
    for (int i = 0; i < n_in; ++i) {
        switch (in_sizes[i]) {
            case BATCH * HW0 * NC: cls0 = (const float*)d_in[i]; break;
            case BATCH * HW1 * NC: cls1 = (const float*)d_in[i]; break;
            case BATCH * HW2 * NC: cls2 = (const float*)d_in[i]; break;
            case BATCH * HW0 * 4:  reg0 = (const float*)d_in[i]; break;
            case BATCH * HW1 * 4:  reg1 = (const float*)d_in[i]; break;
            case BATCH * HW2 * 4:  reg2 = (const float*)d_in[i]; break;
            case BATCH * NGT * 4:  gt_boxes = (const float*)d_in[i]; break;
            case BATCH * NGT:      gt_labels = (const int*)d_in[i]; break;
            default: break;
        }
    }

    char* ws = (char*)d_ws;
    float* acc = (float*)(ws + ACC_OFF);
    hipMemsetAsync(acc, 0, 3 * sizeof(float), stream);

    const bool pack = (ws_size >= WS_NEEDED);
    unsigned long long* part;
    const int scan_grid = BATCH * SL0 * NCHUNK + 2 * BATCH * NCHUNK;  // 768

    if (pack) {
        float2* xy0 = (float2*)(ws + PACK0_OFF);
        float2* xy1 = (float2*)(ws + PACK1_OFF);
        float2* xy2 = (float2*)(ws + PACK2_OFF);
        part = (unsigned long long*)(ws + PART_OFF);
        const int rows = BATCH * (HW0 + HW1 + HW2);  // 537,600
        pack_kernel<<<(rows + NTH - 1) / NTH, NTH, 0, stream>>>(
            reg0, reg1, reg2, xy0, xy1, xy2);
        scan_kernel<<<scan_grid, NTH, 0, stream>>>(
            xy0, xy1, xy2, 1, gt_boxes, part);
    } else {
        part = (unsigned long long*)(ws + 256);
        scan_kernel<<<scan_grid, NTH, 0, stream>>>(
            (const float2*)reg0, (const float2*)reg1, (const float2*)reg2, 2,
            gt_boxes, part);
    }

    loss_kernel<<<(3 * BATCH * NGT) / 4, NTH, 0, stream>>>(
        cls0, cls1, cls2, reg0, reg1, reg2, gt_boxes, gt_labels, part, acc);

    finalize_kernel<<<1, 1, 0, stream>>>(acc, (float*)d_out);
}

// Round 4
// 220.772 us; speedup vs baseline: 2.0489x; 2.0489x over previous
//
#include <hip/hip_runtime.h>
#include <cstdint>
#include <cstddef>

#define NTH 256
#define NGT 128
#define BATCH 16
#define NC 80
#define G 16                  // GTs per scan block
#define NCHUNK (NGT / G)      // 8
#define HW0 25600
#define HW1 6400
#define HW2 1600
#define SL0 4                 // hw slices for level 0
#define MAXSL 4
#define NLOSS_BLK (3 * BATCH * NGT / 4)   // 1536 loss blocks (4 GTs each)

// ws layout (bytes), pack branch
#define PACK0_OFF 0
#define PACK1_OFF (PACK0_OFF + BATCH * HW0 * 8)
#define PACK2_OFF (PACK1_OFF + BATCH * HW1 * 8)
#define PART_OFF  (PACK2_OFF + BATCH * HW2 * 8)
#define PART_BYTES (3 * BATCH * NGT * MAXSL * 8)
#define PARTL_OFF (PART_OFF + PART_BYTES)
#define PARTL_BYTES (NLOSS_BLK * 3 * sizeof(float))
#define WS_NEEDED (PARTL_OFF + (size_t)PARTL_BYTES)

__device__ __forceinline__ unsigned long long umin64(unsigned long long a, unsigned long long b) {
    return a < b ? a : b;
}

// Prepass: pack each 16-B reg row's xy into a contiguous float2 array.
__global__ __launch_bounds__(NTH) void pack_kernel(
    const float* __restrict__ reg0, const float* __restrict__ reg1, const float* __restrict__ reg2,
    float2* __restrict__ xy0, float2* __restrict__ xy1, float2* __restrict__ xy2)
{
    int r = blockIdx.x * NTH + threadIdx.x;
    const int N0 = BATCH * HW0, N1 = BATCH * HW1, N2 = BATCH * HW2;
    if (r < N0) {
        float4 v = reinterpret_cast<const float4*>(reg0)[r];
        xy0[r] = make_float2(v.x, v.y);
    } else if (r < N0 + N1) {
        int i = r - N0;
        float4 v = reinterpret_cast<const float4*>(reg1)[i];
        xy1[i] = make_float2(v.x, v.y);
    } else if (r < N0 + N1 + N2) {
        int i = r - N0 - N1;
        float4 v = reinterpret_cast<const float4*>(reg2)[i];
        xy2[i] = make_float2(v.x, v.y);
    }
}

#define EVAL(px, py, idx_) do {                                                   \
    _Pragma("unroll")                                                             \
    for (int g = 0; g < G; ++g) {                                                 \
        float dx = gx[g] - (px), dy = gy[g] - (py);                               \
        float d2 = dx * dx + dy * dy;                                             \
        unsigned long long key =                                                  \
            ((unsigned long long)__float_as_uint(d2) << 32) | (unsigned)(idx_);   \
        kmin[g] = umin64(kmin[g], key);                                           \
    } } while (0)

// Scan: one block per (level, batch, hw-slice, chunk-of-16-GTs).
// u64 key (d2 bits << 32 | idx): min == min-d2 with first-index tie-break,
// exactly matching jnp.argmin.
__global__ __launch_bounds__(NTH) void scan_kernel(
    const float2* __restrict__ xy0, const float2* __restrict__ xy1, const float2* __restrict__ xy2,
    int stride2,  // 1 = packed xy, 2 = raw reg rows
    const float* __restrict__ gt_boxes,
    unsigned long long* __restrict__ part)
{
    int x = blockIdx.x;
    int lvl, b, slice, chunk, HW, nsl;
    const float2* src;
    if (x < BATCH * SL0 * NCHUNK) {                         // 512 lvl-0 blocks
        lvl = 0; b = x / (SL0 * NCHUNK);
        int r = x % (SL0 * NCHUNK);
        slice = r / NCHUNK; chunk = r % NCHUNK;
        HW = HW0; nsl = SL0; src = xy0;
    } else if (x < BATCH * SL0 * NCHUNK + BATCH * NCHUNK) { // 128 lvl-1 blocks
        int y = x - BATCH * SL0 * NCHUNK;
        lvl = 1; b = y / NCHUNK; chunk = y % NCHUNK; slice = 0;
        HW = HW1; nsl = 1; src = xy1;
    } else {                                                // 128 lvl-2 blocks
        int y = x - BATCH * SL0 * NCHUNK - BATCH * NCHUNK;
        lvl = 2; b = y / NCHUNK; chunk = y % NCHUNK; slice = 0;
        HW = HW2; nsl = 1; src = xy2;
    }

    const int seg = HW / nsl;
    const int e0 = slice * seg, e1 = e0 + seg;
    const int tid = threadIdx.x, wave = tid >> 6, lane = tid & 63;
    const int n0 = chunk * G;

    float gx[G], gy[G];
#pragma unroll
    for (int g = 0; g < G; ++g) {
        const float* gb = gt_boxes + (size_t)(b * NGT + n0 + g) * 4;
        gx[g] = gb[0]; gy[g] = gb[1];
    }

    unsigned long long kmin[G];
#pragma unroll
    for (int g = 0; g < G; ++g) kmin[g] = ~0ull;

    if (stride2 == 1) {
        const float4* b4 = reinterpret_cast<const float4*>(src + (size_t)b * HW);
        for (int i = e0 / 2 + tid; i < e1 / 2; i += NTH) {
            float4 p = b4[i];
            int i0 = 2 * i;
            EVAL(p.x, p.y, i0);
            EVAL(p.z, p.w, i0 + 1);
        }
    } else {
        const float2* base = src + (size_t)b * HW * 2;
        for (int i = e0 + tid; i < e1; i += NTH) {
            float2 p = base[(size_t)i * 2];
            EVAL(p.x, p.y, i);
        }
    }

#pragma unroll
    for (int g = 0; g < G; ++g) {
#pragma unroll
        for (int off = 32; off >= 1; off >>= 1) {
            unsigned long long o = __shfl_down(kmin[g], off, 64);
            kmin[g] = umin64(kmin[g], o);
        }
    }

    __shared__ unsigned long long smem[G][4];
    if (lane == 0) {
#pragma unroll
        for (int g = 0; g < G; ++g) smem[g][wave] = kmin[g];
    }
    __syncthreads();

    if (tid < G) {
        unsigned long long key = umin64(umin64(smem[tid][0], smem[tid][1]),
                                        umin64(smem[tid][2], smem[tid][3]));
        part[((size_t)(lvl * BATCH + b) * NGT + n0 + tid) * MAXSL + slice] = key;
    }
}

// Loss: one wave per (level, batch, gt); 4 waves per block. NO ATOMICS —
// block reduces its 4 (ce,l1,w) triples in LDS and writes ONE partial triple
// to a distinct slot. (R3 post-mortem: 18K same-address atomicAdds serialized
// at ~31 cyc each = 239 us; this removes them entirely.)
__global__ __launch_bounds__(NTH) void loss_kernel(
    const float* __restrict__ cls0, const float* __restrict__ cls1, const float* __restrict__ cls2,
    const float* __restrict__ reg0, const float* __restrict__ reg1, const float* __restrict__ reg2,
    const float* __restrict__ gt_boxes, const int* __restrict__ gt_labels,
    const unsigned long long* __restrict__ part, float* __restrict__ partl)
{
    const int wave = threadIdx.x >> 6;
    const int lane = threadIdx.x & 63;
    const int gid = blockIdx.x * 4 + wave;     // 0..6143
    const int lvl = gid / (BATCH * NGT);
    const int r = gid % (BATCH * NGT);
    const int b = r / NGT, n = r % NGT;

    const float* cls; const float* reg; int HW, S;
    if (lvl == 0)      { cls = cls0; reg = reg0; HW = HW0; S = SL0; }
    else if (lvl == 1) { cls = cls1; reg = reg1; HW = HW1; S = 1; }
    else               { cls = cls2; reg = reg2; HW = HW2; S = 1; }

    const unsigned long long* p = part + (size_t)gid * MAXSL;
    unsigned long long key = p[0];
    for (int s = 1; s < S; ++s) key = umin64(key, p[s]);

    int match = (int)(unsigned)(key & 0xffffffffu);
    float d2min = __uint_as_float((unsigned)(key >> 32));
    bool valid = d2min < 6.25f;  // sqrt(d2) < 2.5

    const int label = gt_labels[b * NGT + n];
    const float* c = cls + ((size_t)b * HW + match) * NC;

    // 80-class log-softmax across the wave
    float x1 = c[lane];
    float x2 = (lane < NC - 64) ? c[64 + lane] : -INFINITY;
    float mx = fmaxf(x1, x2);
#pragma unroll
    for (int off = 32; off >= 1; off >>= 1) mx = fmaxf(mx, __shfl_xor(mx, off, 64));
    float s = expf(x1 - mx) + ((lane < NC - 64) ? expf(x2 - mx) : 0.0f);
#pragma unroll
    for (int off = 32; off >= 1; off >>= 1) s += __shfl_xor(s, off, 64);

    __shared__ float ce_s[4], l1_s[4], w_s[4];
    if (lane == 0) {
        float ce = 0.0f, l1 = 0.0f, w = 0.0f;
        if (valid) {
            float xlab = c[label];
            ce = -(xlab - mx - logf(s));
            const float* gb = gt_boxes + (size_t)(b * NGT + n) * 4;
            const float* gr = reg + ((size_t)b * HW + match) * 4;
            l1 = fabsf(gr[0] - gb[0]) + fabsf(gr[1] - gb[1]) +
                 fabsf(gr[2] - gb[2]) + fabsf(gr[3] - gb[3]);
            w = 1.0f;
        }
        ce_s[wave] = ce; l1_s[wave] = l1; w_s[wave] = w;
    }
    __syncthreads();

    if (threadIdx.x == 0) {
        float* o = partl + (size_t)blockIdx.x * 3;
        o[0] = ce_s[0] + ce_s[1] + ce_s[2] + ce_s[3];
        o[1] = l1_s[0] + l1_s[1] + l1_s[2] + l1_s[3];
        o[2] = w_s[0] + w_s[1] + w_s[2] + w_s[3];
    }
}

// Deterministic tree reduction of the 1536 partial triples; writes outputs.
__global__ __launch_bounds__(NTH) void finalize_kernel(
    const float* __restrict__ partl, float* __restrict__ out)
{
    const int tid = threadIdx.x, wave = tid >> 6, lane = tid & 63;
    float ce = 0.0f, l1 = 0.0f, w = 0.0f;
    for (int i = tid; i < NLOSS_BLK; i += NTH) {
        ce += partl[(size_t)i * 3 + 0];
        l1 += partl[(size_t)i * 3 + 1];
        w  += partl[(size_t)i * 3 + 2];
    }
#pragma unroll
    for (int off = 32; off >= 1; off >>= 1) {
        ce += __shfl_xor(ce, off, 64);
        l1 += __shfl_xor(l1, off, 64);
        w  += __shfl_xor(w,  off, 64);
    }
    __shared__ float sm[3][4];
    if (lane == 0) { sm[0][wave] = ce; sm[1][wave] = l1; sm[2][wave] = w; }
    __syncthreads();
    if (tid == 0) {
        float tce = sm[0][0] + sm[0][1] + sm[0][2] + sm[0][3];
        float tl1 = sm[1][0] + sm[1][1] + sm[1][2] + sm[1][3];
        float tw  = sm[2][0] + sm[2][1] + sm[2][2] + sm[2][3];
        float denom = fmaxf(tw, 1.0f);
        out[0] = tce / denom;
        out[1] = tl1 / denom;
        out[2] = tw;
    }
}

extern "C" void kernel_launch(void* const* d_in, const int* in_sizes, int n_in,
                              void* d_out, int out_size, void* d_ws, size_t ws_size,
                              hipStream_t stream) {
    // Map inputs BY SIZE (dict order interleaves cls/reg; all sizes distinct).
    const float* cls0 = nullptr; const float* cls1 = nullptr; const float* cls2 = nullptr;
    const float* reg0 = nullptr; const float* reg1 = nullptr; const float* reg2 = nullptr;
    const float* gt_boxes = nullptr; const int* gt_labels = nullptr;
    for (int i = 0; i < n_in; ++i) {
        switch (in_sizes[i]) {
            case BATCH * HW0 * NC: cls0 = (const float*)d_in[i]; break;
            case BATCH * HW1 * NC: cls1 = (const float*)d_in[i]; break;
            case BATCH * HW2 * NC: cls2 = (const float*)d_in[i]; break;
            case BATCH * HW0 * 4:  reg0 = (const float*)d_in[i]; break;
            case BATCH * HW1 * 4:  reg1 = (const float*)d_in[i]; break;
            case BATCH * HW2 * 4:  reg2 = (const float*)d_in[i]; break;
            case BATCH * NGT * 4:  gt_boxes = (const float*)d_in[i]; break;
            case BATCH * NGT:      gt_labels = (const int*)d_in[i]; break;
            default: break;
        }
    }

    char* ws = (char*)d_ws;
    const bool pack = (ws_size >= WS_NEEDED);
    unsigned long long* part;
    float* partl;
    const int scan_grid = BATCH * SL0 * NCHUNK + 2 * BATCH * NCHUNK;  // 768

    if (pack) {
        float2* xy0 = (float2*)(ws + PACK0_OFF);
        float2* xy1 = (float2*)(ws + PACK1_OFF);
        float2* xy2 = (float2*)(ws + PACK2_OFF);
        part  = (unsigned long long*)(ws + PART_OFF);
        partl = (float*)(ws + PARTL_OFF);
        const int rows = BATCH * (HW0 + HW1 + HW2);  // 537,600
        pack_kernel<<<(rows + NTH - 1) / NTH, NTH, 0, stream>>>(
            reg0, reg1, reg2, xy0, xy1, xy2);
        scan_kernel<<<scan_grid, NTH, 0, stream>>>(
            xy0, xy1, xy2, 1, gt_boxes, part);
    } else {
        part  = (unsigned long long*)(ws);
        partl = (float*)(ws + PART_BYTES);
        scan_kernel<<<scan_grid, NTH, 0, stream>>>(
            (const float2*)reg0, (const float2*)reg1, (const float2*)reg2, 2,
            gt_boxes, part);
    }

    loss_kernel<<<NLOSS_BLK, NTH, 0, stream>>>(
        cls0, cls1, cls2, reg0, reg1, reg2, gt_boxes, gt_labels, part, partl);

    finalize_kernel<<<1, NTH, 0, stream>>>(partl, (float*)d_out);
}